// Round 1
// baseline (1513.802 us; speedup 1.0000x reference)
//
#include <hip/hip_runtime.h>
#include <math.h>

#define HH 192
#define WW 192
#define HWP (192*192)
#define BB 4
#define CF 64
#define NC 7
#define OO 64
#define PIX_BLOCKS (HWP/256)   // 144

// ---------------- depthwise conv (SAME, groups=C) ----------------
template<int k>
__global__ __launch_bounds__(256)
void dw_kernel(const float* __restrict__ fea, const float* __restrict__ w,
               const float* __restrict__ bias, float* __restrict__ out) {
    int idx = blockIdx.x * 256 + threadIdx.x;   // over B*CF*HW
    if (idx >= BB * CF * HWP) return;
    int wpos = idx % WW;
    int hpos = (idx / WW) % HH;
    int plane = idx / HWP;        // b*CF + c
    int c = plane % CF;
    const float* f = fea + (size_t)plane * HWP;
    const int pad = k / 2;
    float acc = 0.f;
#pragma unroll
    for (int dy = 0; dy < k; ++dy) {
        int y = hpos + dy - pad;
        if (y < 0 || y >= HH) continue;
#pragma unroll
        for (int dx = 0; dx < k; ++dx) {
            int x = wpos + dx - pad;
            if (x < 0 || x >= WW) continue;
            acc += f[y * WW + x] * w[c * k * k + dy * k + dx];
        }
    }
    out[idx] = acc + bias[c];
}

// ---------------- generic small transpose (rows,cols) -> (cols,rows) ------
__global__ void transpose_kernel(const float* __restrict__ in, float* __restrict__ out,
                                 int rows, int cols) {
    int idx = blockIdx.x * 256 + threadIdx.x;
    if (idx >= rows * cols) return;
    int r = idx / cols, c = idx % cols;
    out[c * rows + r] = in[idx];
}

// ---------------- fused pw-conv (offset/mask) + deformable conv + relu ----
template<int k>
__global__ __launch_bounds__(256)
void branch_kernel(const float* __restrict__ dwout,
                   const float* __restrict__ pw_w, const float* __restrict__ pw_b,
                   const float* __restrict__ inputs,
                   const float* __restrict__ dcn_wt,   // (7K, 64)
                   const float* __restrict__ dcn_b,
                   float* __restrict__ outbuf, int t) {
    constexpr int K = k * k;
    constexpr int pad = k / 2;
    int blk = blockIdx.x;                 // 0..575
    int b = blk / PIX_BLOCKS;
    int p = (blk % PIX_BLOCKS) * 256 + threadIdx.x;
    int h = p / WW, wq = p % WW;

    float dw[CF];
    {
        const float* dwp = dwout + (size_t)(b * CF) * HWP + p;
#pragma unroll
        for (int c = 0; c < CF; ++c) dw[c] = dwp[(size_t)c * HWP];
    }

    float acc[OO];
#pragma unroll
    for (int o = 0; o < OO; ++o) acc[o] = 0.f;

    const float* inb = inputs + (size_t)b * NC * HWP;

    for (int c = 0; c < NC; ++c) {
        const float* inc = inb + (size_t)c * HWP;
        for (int kk = 0; kk < K; ++kk) {
            int r_y = (c * K + kk) * 2;
            int r_x = r_y + 1;
            int r_m = 14 * K + c * K + kk;
            const float* wy = pw_w + (size_t)r_y * CF;
            const float* wx = pw_w + (size_t)r_x * CF;
            const float* wm = pw_w + (size_t)r_m * CF;
            float oy = pw_b[r_y], ox = pw_b[r_x], om = pw_b[r_m];
#pragma unroll
            for (int j = 0; j < CF; ++j) {
                oy += wy[j] * dw[j];
                ox += wx[j] * dw[j];
                om += wm[j] * dw[j];
            }
            float m = 1.f / (1.f + expf(-om));
            float py = oy + (float)(kk / k + h - pad);
            float px = ox + (float)(kk % k + wq - pad);
            float y0 = floorf(py), x0 = floorf(px);
            float wyf = py - y0, wxf = px - x0;
            int iy0 = (int)y0, ix0 = (int)x0;
            bool y0v = (iy0 >= 0) && (iy0 < HH);
            bool y1v = (iy0 + 1 >= 0) && (iy0 + 1 < HH);
            bool x0v = (ix0 >= 0) && (ix0 < WW);
            bool x1v = (ix0 + 1 >= 0) && (ix0 + 1 < WW);
            int yc0 = min(max(iy0, 0), HH - 1), yc1 = min(max(iy0 + 1, 0), HH - 1);
            int xc0 = min(max(ix0, 0), WW - 1), xc1 = min(max(ix0 + 1, 0), WW - 1);
            float v00 = 0.f, v01 = 0.f, v10 = 0.f, v11 = 0.f;
            if (y0v) {
                if (x0v) v00 = inc[yc0 * WW + xc0];
                if (x1v) v01 = inc[yc0 * WW + xc1];
            }
            if (y1v) {
                if (x0v) v10 = inc[yc1 * WW + xc0];
                if (x1v) v11 = inc[yc1 * WW + xc1];
            }
            float s = (v00 * (1.f - wyf) * (1.f - wxf) + v01 * (1.f - wyf) * wxf +
                       v10 * wyf * (1.f - wxf) + v11 * wyf * wxf) * m;
            const float* dt = dcn_wt + (size_t)(c * K + kk) * OO;
#pragma unroll
            for (int o = 0; o < OO; ++o) acc[o] += s * dt[o];
        }
    }
    float* op = outbuf + (size_t)((b * 3 + t) * OO) * HWP + p;
#pragma unroll
    for (int o = 0; o < OO; ++o) {
        float v = acc[o] + dcn_b[o];
        op[(size_t)o * HWP] = v > 0.f ? v : 0.f;
    }
}

// ---------------- attention: per-block partial sums of relu(attn pw) ------
__global__ __launch_bounds__(256)
void attn_sum_kernel(const float* __restrict__ outbuf, const float* __restrict__ attn_wt,
                     const float* __restrict__ attn_b, float* __restrict__ partial) {
    int blk = blockIdx.x;
    int b = blk / PIX_BLOCKS;
    int pb = blk % PIX_BLOCKS;
    int p = pb * 256 + threadIdx.x;
    const float* ob = outbuf + (size_t)(b * 192) * HWP + p;
    float acc[OO];
#pragma unroll
    for (int o = 0; o < OO; ++o) acc[o] = attn_b[o];
    for (int c = 0; c < 192; ++c) {
        float v = ob[(size_t)c * HWP];
        const float* wt = attn_wt + c * OO;
#pragma unroll
        for (int o = 0; o < OO; ++o) acc[o] += v * wt[o];
    }
    __shared__ float red[4][OO];
    int lane = threadIdx.x & 63, wv = threadIdx.x >> 6;
#pragma unroll
    for (int o = 0; o < OO; ++o) {
        float v = acc[o] > 0.f ? acc[o] : 0.f;
        v += __shfl_down(v, 32);
        v += __shfl_down(v, 16);
        v += __shfl_down(v, 8);
        v += __shfl_down(v, 4);
        v += __shfl_down(v, 2);
        v += __shfl_down(v, 1);
        if (lane == 0) red[wv][o] = v;
    }
    __syncthreads();
    if (threadIdx.x < OO) {
        int o = threadIdx.x;
        partial[(size_t)(b * PIX_BLOCKS + pb) * OO + o] =
            red[0][o] + red[1][o] + red[2][o] + red[3][o];
    }
}

// ---------------- attention finish: mean -> fc(relu) -> per-branch scales -
__global__ void attn_finish_kernel(const float* __restrict__ partial,
                                   const float* __restrict__ fc_w, const float* __restrict__ fc_b,
                                   const float* __restrict__ fcs_w0, const float* __restrict__ fcs_b0,
                                   const float* __restrict__ fcs_w1, const float* __restrict__ fcs_b1,
                                   const float* __restrict__ fcs_w2, const float* __restrict__ fcs_b2,
                                   float* __restrict__ atts) {
    int b = blockIdx.x;
    __shared__ float attm[OO];
    __shared__ float fcv[32];
    int tid = threadIdx.x;   // 64 threads
    if (tid < OO) {
        float s = 0.f;
        for (int blk = 0; blk < PIX_BLOCKS; ++blk)
            s += partial[(size_t)(b * PIX_BLOCKS + blk) * OO + tid];
        attm[tid] = s / (float)HWP;
    }
    __syncthreads();
    if (tid < 32) {
        float s = fc_b[tid];
        for (int o = 0; o < OO; ++o) s += fc_w[tid * OO + o] * attm[o];
        fcv[tid] = s > 0.f ? s : 0.f;
    }
    __syncthreads();
    if (tid < OO) {
        {
            float s = fcs_b0[tid];
            for (int j = 0; j < 32; ++j) s += fcs_w0[tid * 32 + j] * fcv[j];
            atts[b * 192 + 0 * OO + tid] = s;
        }
        {
            float s = fcs_b1[tid];
            for (int j = 0; j < 32; ++j) s += fcs_w1[tid * 32 + j] * fcv[j];
            atts[b * 192 + 1 * OO + tid] = s;
        }
        {
            float s = fcs_b2[tid];
            for (int j = 0; j < 32; ++j) s += fcs_w2[tid * 32 + j] * fcv[j];
            atts[b * 192 + 2 * OO + tid] = s;
        }
    }
}

// ---------------- final: scale + 1x1 conv + relu ----------------
__global__ __launch_bounds__(256)
void final_kernel(const float* __restrict__ outbuf, const float* __restrict__ atts,
                  const float* __restrict__ conv_wt, const float* __restrict__ conv_b,
                  float* __restrict__ out) {
    int blk = blockIdx.x;
    int b = blk / PIX_BLOCKS;
    int p = (blk % PIX_BLOCKS) * 256 + threadIdx.x;
    const float* ob = outbuf + (size_t)(b * 192) * HWP + p;
    const float* at = atts + b * 192;
    float acc[OO];
#pragma unroll
    for (int o = 0; o < OO; ++o) acc[o] = conv_b[o];
    for (int c = 0; c < 192; ++c) {
        float v = ob[(size_t)c * HWP] * at[c];
        const float* wt = conv_wt + c * OO;
#pragma unroll
        for (int o = 0; o < OO; ++o) acc[o] += v * wt[o];
    }
    float* op = out + (size_t)(b * OO) * HWP + p;
#pragma unroll
    for (int o = 0; o < OO; ++o) op[(size_t)o * HWP] = acc[o] > 0.f ? acc[o] : 0.f;
}

extern "C" void kernel_launch(void* const* d_in, const int* in_sizes, int n_in,
                              void* d_out, int out_size, void* d_ws, size_t ws_size,
                              hipStream_t stream) {
    const float* fea    = (const float*)d_in[0];
    const float* inputs = (const float*)d_in[1];
    const float* dw_w[3]  = {(const float*)d_in[2],  (const float*)d_in[8],  (const float*)d_in[14]};
    const float* dw_b[3]  = {(const float*)d_in[3],  (const float*)d_in[9],  (const float*)d_in[15]};
    const float* pw_w[3]  = {(const float*)d_in[4],  (const float*)d_in[10], (const float*)d_in[16]};
    const float* pw_b[3]  = {(const float*)d_in[5],  (const float*)d_in[11], (const float*)d_in[17]};
    const float* dcn_w[3] = {(const float*)d_in[6],  (const float*)d_in[12], (const float*)d_in[18]};
    const float* dcn_b[3] = {(const float*)d_in[7],  (const float*)d_in[13], (const float*)d_in[19]};
    const float* attn_w = (const float*)d_in[20];
    const float* attn_b = (const float*)d_in[21];
    const float* fc_w   = (const float*)d_in[22];
    const float* fc_b   = (const float*)d_in[23];
    const float* fcs_w[3] = {(const float*)d_in[24], (const float*)d_in[26], (const float*)d_in[28]};
    const float* fcs_b[3] = {(const float*)d_in[25], (const float*)d_in[27], (const float*)d_in[29]};
    const float* conv_w = (const float*)d_in[30];
    const float* conv_b = (const float*)d_in[31];
    float* out = (float*)d_out;

    // workspace carve (floats)
    float* W = (float*)d_ws;
    float* outbuf  = W;                         // 4*192*36864 = 28,311,552
    float* dwout   = outbuf + 28311552;         // 4*64*36864  = 9,437,184
    float* partial = dwout + 9437184;           // 4*144*64    = 36,864
    float* atts    = partial + 36864;           // 768
    float* dcn_wt  = atts + 768;                // up to 7*25*64 = 11,200
    float* attn_wt = dcn_wt + 11200;            // 192*64 = 12,288
    float* conv_wt = attn_wt + 12288;           // 192*64 = 12,288

    // transpose 192x64 weight matrices once per call
    transpose_kernel<<<(192 * 64 + 255) / 256, 256, 0, stream>>>(attn_w, attn_wt, 64, 192);
    transpose_kernel<<<(192 * 64 + 255) / 256, 256, 0, stream>>>(conv_w, conv_wt, 64, 192);

    const int dw_grid = (BB * CF * HWP) / 256;   // 36864
    const int pix_grid = BB * PIX_BLOCKS;        // 576

    // branch 0 (k=1)
    dw_kernel<1><<<dw_grid, 256, 0, stream>>>(fea, dw_w[0], dw_b[0], dwout);
    transpose_kernel<<<(7 * 1 * 64 + 255) / 256, 256, 0, stream>>>(dcn_w[0], dcn_wt, 64, 7 * 1);
    branch_kernel<1><<<pix_grid, 256, 0, stream>>>(dwout, pw_w[0], pw_b[0], inputs,
                                                   dcn_wt, dcn_b[0], outbuf, 0);
    // branch 1 (k=3)
    dw_kernel<3><<<dw_grid, 256, 0, stream>>>(fea, dw_w[1], dw_b[1], dwout);
    transpose_kernel<<<(7 * 9 * 64 + 255) / 256, 256, 0, stream>>>(dcn_w[1], dcn_wt, 64, 7 * 9);
    branch_kernel<3><<<pix_grid, 256, 0, stream>>>(dwout, pw_w[1], pw_b[1], inputs,
                                                   dcn_wt, dcn_b[1], outbuf, 1);
    // branch 2 (k=5)
    dw_kernel<5><<<dw_grid, 256, 0, stream>>>(fea, dw_w[2], dw_b[2], dwout);
    transpose_kernel<<<(7 * 25 * 64 + 255) / 256, 256, 0, stream>>>(dcn_w[2], dcn_wt, 64, 7 * 25);
    branch_kernel<5><<<pix_grid, 256, 0, stream>>>(dwout, pw_w[2], pw_b[2], inputs,
                                                   dcn_wt, dcn_b[2], outbuf, 2);

    // attention
    attn_sum_kernel<<<pix_grid, 256, 0, stream>>>(outbuf, attn_wt, attn_b, partial);
    attn_finish_kernel<<<BB, 64, 0, stream>>>(partial, fc_w, fc_b,
                                              fcs_w[0], fcs_b[0], fcs_w[1], fcs_b[1],
                                              fcs_w[2], fcs_b[2], atts);
    // final conv
    final_kernel<<<pix_grid, 256, 0, stream>>>(outbuf, atts, conv_wt, conv_b, out);
}